// Round 6
// baseline (337.334 us; speedup 1.0000x reference)
//
#include <hip/hip_runtime.h>
#include <hip/hip_bf16.h>

// B=256 batch, N=8192 rows, C=32768 cols, NSE=524288 edges (rows sorted,
// every row present at least once).
#define BB   256
#define NN   8192
#define CC   32768
#define NSE_ 524288
#define GB   32                                 // batches per XCD group
#define NTILES (NN / 16)                        // 512 row-tiles per group
#define PREP_BLOCKS ((NSE_ + 64 + 255) / 256)   // 2049
#define TP_BLOCKS   ((CC / 64) * 8)             // 4096

typedef float v2f __attribute__((ext_vector_type(2)));

__device__ __forceinline__ unsigned int f2bf_rne(float f) {
    unsigned int u = __float_as_uint(f);
    return (u + 0x7fffu + ((u >> 16) & 1u)) >> 16;   // round-to-nearest-even
}
__device__ __forceinline__ unsigned int pack2bf(float lo, float hi) {
    return f2bf_rne(lo) | (f2bf_rne(hi) << 16);
}

// ---------------------------------------------------------------------------
// Fused prep + transpose (two independent block ranges).
//  [0, PREP_BLOCKS): cw[e]=(col, exp(log_w)) uint2 (+64 zero pads), CSR
//                    row_start, and zeroing of the 8 work-queue counters.
//  [PREP_BLOCKS, +TP_BLOCKS): cet[g][c][bl] = bf16(exp(ll[g*32+bl][c])),
//    layout [8][CC][32] bf16; bf16 pairs packed BEFORE LDS, b128 LDS ops,
//    contiguous 1KB/wave global writes.
// ---------------------------------------------------------------------------
__global__ __launch_bounds__(256) void prep_transpose_kernel(
    const float* __restrict__ lw, const int* __restrict__ rows,
    const int* __restrict__ cols, const float* __restrict__ ll,
    uint2* __restrict__ cw, int* __restrict__ rs,
    unsigned int* __restrict__ cet32, int* __restrict__ cnt) {
    int bid = blockIdx.x;
    int t = threadIdx.x;
    if (bid < PREP_BLOCKS) {
        if (bid == 0 && t < 8) cnt[t] = 0;      // work-queue counters
        int e = bid * 256 + t;
        if (e < NSE_) {
            cw[e] = make_uint2((unsigned)cols[e],
                               __float_as_uint(__expf(lw[e])));
            if (e == 0) { rs[0] = 0; rs[NN] = NSE_; }
            else if (rows[e] != rows[e - 1]) rs[rows[e]] = e;
        } else if (e < NSE_ + 64) {
            cw[e] = make_uint2(0u, 0u);         // col=0 (safe), w=0
        }
        return;
    }
    bid -= PREP_BLOCKS;
    int g = bid & 7;
    int ct = bid >> 3;
    int c0 = ct * 64, b0 = g * GB;
    __shared__ unsigned int tile_u[16][68];     // [batch_pair][c_local]
    {
        int c4 = t & 15, bp = t >> 4;
        const float4 fa = *reinterpret_cast<const float4*>(
            ll + (size_t)(b0 + 2 * bp + 0) * CC + c0 + 4 * c4);
        const float4 fb = *reinterpret_cast<const float4*>(
            ll + (size_t)(b0 + 2 * bp + 1) * CC + c0 + 4 * c4);
        uint4 u;
        u.x = pack2bf(__expf(fa.x), __expf(fb.x));
        u.y = pack2bf(__expf(fa.y), __expf(fb.y));
        u.z = pack2bf(__expf(fa.z), __expf(fb.z));
        u.w = pack2bf(__expf(fa.w), __expf(fb.w));
        *reinterpret_cast<uint4*>(&tile_u[bp][4 * c4]) = u;
    }
    __syncthreads();
    {
        int c = t >> 2, q = t & 3;
        uint4 o;
        o.x = tile_u[4 * q + 0][c];
        o.y = tile_u[4 * q + 1][c];
        o.z = tile_u[4 * q + 2][c];
        o.w = tile_u[4 * q + 3][c];
        size_t base_u = ((size_t)g * CC + c0) * 16;
        *reinterpret_cast<uint4*>(cet32 + base_u + c * 16 + 4 * q) = o;
    }
}

// ---------------------------------------------------------------------------
// Main gather-accumulate with XCD-pinned work queues.
// Each block reads its actual XCD (HW_REG_XCC_ID = hwreg 20) and claims
// 16-row tiles from that XCD's queue (atomic counter), stealing from other
// queues when empty -> every gather hits the local 2 MiB L2-resident slice
// regardless of the block->XCD dispatch mapping.
// Per wave: TWO adjacent rows as independent streams (8 gathers in flight).
// Lane = (grp = lane>>2 edge slot 0..15, bq = lane&3 batch octet).
// ---------------------------------------------------------------------------
__global__ __launch_bounds__(256) void sum_rows_kernel(
    const uint2* __restrict__ cw, const int* __restrict__ rs,
    const uint4* __restrict__ cet, int* __restrict__ cnt,
    float* __restrict__ out) {
    __shared__ uint2 stage[4][2][64];
    __shared__ float lds_out[32][17];
    __shared__ int tile_sh;
    int wv = threadIdx.x >> 6;
    int lane = threadIdx.x & 63;
    int grp = lane >> 2;                // 0..15 edge slot
    int bq = lane & 3;                  // 0..3 batch octet
    // HW_REG_XCC_ID: id=20, offset=0, width=8  (verified readable on gfx950)
    int xcd = __builtin_amdgcn_s_getreg(20 | (7 << 11)) & 7;

    for (int k = 0; k < 8; ++k) {
        int g = (xcd + k) & 7;
        const uint4* slice = cet + (size_t)g * CC * 4;   // 4 uint4 per col
        for (;;) {
            __syncthreads();            // protects tile_sh + lds_out reuse
            if (threadIdx.x == 0) tile_sh = atomicAdd(&cnt[g], 1);
            __syncthreads();
            int ntile = tile_sh;
            if (ntile >= NTILES) break;
            int n0 = ntile * 16;

            for (int rp = 0; rp < 2; ++rp) {
                int nA = n0 + wv * 4 + rp * 2;          // rows nA, nA+1
                int sA = __builtin_amdgcn_readfirstlane(rs[nA]);
                int tA = __builtin_amdgcn_readfirstlane(rs[nA + 1]);
                int sB = tA;
                int tB = __builtin_amdgcn_readfirstlane(rs[nA + 2]);
                v2f aA[4], aB[4];
                aA[0] = 0.f; aA[1] = 0.f; aA[2] = 0.f; aA[3] = 0.f;
                aB[0] = 0.f; aB[1] = 0.f; aB[2] = 0.f; aB[3] = 0.f;
                float zA = 0.f, zB = 0.f;
                uint2* stA = stage[wv][0];
                uint2* stB = stage[wv][1];
                uint2 vA = cw[sA + lane];               // pad-safe
                uint2 vB = cw[sB + lane];
                int ebA = sA, ebB = sB;
                while (ebA < tA || ebB < tB) {
                    uint2 wA = vA, wB = vB;
                    if (ebA + lane >= tA) wA.y = 0u;    // mask foreign/pad
                    if (ebB + lane >= tB) wB.y = 0u;
                    stA[lane] = wA;
                    stB[lane] = wB;
                    if (ebA + 64 < tA) vA = cw[ebA + 64 + lane];
                    if (ebB + 64 < tB) vB = cw[ebB + 64 + lane];
                    #pragma unroll
                    for (int j = 0; j < 4; ++j) {
                        uint2 pA = stA[j * 16 + grp];
                        uint2 pB = stB[j * 16 + grp];
                        uint4 uA = slice[(pA.x << 2) | bq];
                        uint4 uB = slice[(pB.x << 2) | bq];
                        float wa = __uint_as_float(pA.y);
                        float wb = __uint_as_float(pB.y);
                        v2f w2a; w2a.x = wa; w2a.y = wa;
                        v2f w2b; w2b.x = wb; w2b.y = wb;
                        v2f q0, q1, q2, q3;
                        q0.x = __uint_as_float(uA.x << 16);
                        q0.y = __uint_as_float(uA.x & 0xffff0000u);
                        q1.x = __uint_as_float(uA.y << 16);
                        q1.y = __uint_as_float(uA.y & 0xffff0000u);
                        q2.x = __uint_as_float(uA.z << 16);
                        q2.y = __uint_as_float(uA.z & 0xffff0000u);
                        q3.x = __uint_as_float(uA.w << 16);
                        q3.y = __uint_as_float(uA.w & 0xffff0000u);
                        aA[0] += w2a * q0;
                        aA[1] += w2a * q1;
                        aA[2] += w2a * q2;
                        aA[3] += w2a * q3;
                        q0.x = __uint_as_float(uB.x << 16);
                        q0.y = __uint_as_float(uB.x & 0xffff0000u);
                        q1.x = __uint_as_float(uB.y << 16);
                        q1.y = __uint_as_float(uB.y & 0xffff0000u);
                        q2.x = __uint_as_float(uB.z << 16);
                        q2.y = __uint_as_float(uB.z & 0xffff0000u);
                        q3.x = __uint_as_float(uB.w << 16);
                        q3.y = __uint_as_float(uB.w & 0xffff0000u);
                        aB[0] += w2b * q0;
                        aB[1] += w2b * q1;
                        aB[2] += w2b * q2;
                        aB[3] += w2b * q3;
                        zA += wa;
                        zB += wb;
                    }
                    ebA += 64;
                    ebB += 64;
                }
                #pragma unroll
                for (int off = 4; off <= 32; off <<= 1) {
                    #pragma unroll
                    for (int q = 0; q < 4; ++q) {
                        aA[q].x += __shfl_xor(aA[q].x, off);
                        aA[q].y += __shfl_xor(aA[q].y, off);
                        aB[q].x += __shfl_xor(aB[q].x, off);
                        aB[q].y += __shfl_xor(aB[q].y, off);
                    }
                    zA += __shfl_xor(zA, off);
                    zB += __shfl_xor(zB, off);
                }
                if (grp == 0) {
                    float lzA = __logf(zA), lzB = __logf(zB);
                    int col = wv * 4 + rp * 2;
                    #pragma unroll
                    for (int q = 0; q < 4; ++q) {
                        lds_out[bq * 8 + q * 2 + 0][col] = __logf(aA[q].x) - lzA;
                        lds_out[bq * 8 + q * 2 + 1][col] = __logf(aA[q].y) - lzA;
                        lds_out[bq * 8 + q * 2 + 0][col + 1] = __logf(aB[q].x) - lzB;
                        lds_out[bq * 8 + q * 2 + 1][col + 1] = __logf(aB[q].y) - lzB;
                    }
                }
            }
            __syncthreads();
            if (threadIdx.x < 128) {
                int bl = threadIdx.x >> 2, ch = threadIdx.x & 3;
                float4 v = make_float4(
                    lds_out[bl][ch * 4 + 0], lds_out[bl][ch * 4 + 1],
                    lds_out[bl][ch * 4 + 2], lds_out[bl][ch * 4 + 3]);
                *reinterpret_cast<float4*>(
                    out + (size_t)(g * GB + bl) * NN + n0 + ch * 4) = v;
            }
        }
    }
}

// ---------------------------------------------------------------------------
extern "C" void kernel_launch(void* const* d_in, const int* in_sizes, int n_in,
                              void* d_out, int out_size, void* d_ws, size_t ws_size,
                              hipStream_t stream) {
    const float* child_ll = (const float*)d_in[0];   // [B, C]
    const float* log_w    = (const float*)d_in[1];   // [NSE]
    const int*   rows     = (const int*)  d_in[2];   // [NSE] sorted
    const int*   cols     = (const int*)  d_in[3];   // [NSE]
    float* out = (float*)d_out;                      // [B, N]

    // ws: [0,6MiB) cw uint2[NSE+64] | [6MiB,+33KB) rs | [7MiB,+32B) cnt
    //     [8MiB,24MiB) cet bf16 slices
    char* ws = (char*)d_ws;
    uint2*        cwp = (uint2*)ws;
    int*          rs  = (int*)(ws + (size_t)6 * 1024 * 1024);
    int*          cnt = (int*)(ws + (size_t)7 * 1024 * 1024);
    unsigned int* cet = (unsigned int*)(ws + (size_t)8 * 1024 * 1024);

    prep_transpose_kernel<<<PREP_BLOCKS + TP_BLOCKS, 256, 0, stream>>>(
        log_w, rows, cols, child_ll, cwp, rs, cet, cnt);
    sum_rows_kernel<<<2048, 256, 0, stream>>>(
        cwp, rs, (const uint4*)cet, cnt, out);
}

// Round 7
// 132.352 us; speedup vs baseline: 2.5488x; 2.5488x over previous
//
#include <hip/hip_runtime.h>
#include <hip/hip_bf16.h>

// B=256 batch, N=8192 rows, C=32768 cols, NSE=524288 edges (rows sorted,
// every row present at least once).
#define BB   256
#define NN   8192
#define CC   32768
#define NSE_ 524288
#define GB   32                                 // batches per XCD group
#define PREP_BLOCKS ((NSE_ + 64 + 255) / 256)   // 2049
#define TP_BLOCKS   ((CC / 64) * 8)             // 4096

typedef float v2f __attribute__((ext_vector_type(2)));

__device__ __forceinline__ unsigned int f2bf_rne(float f) {
    unsigned int u = __float_as_uint(f);
    return (u + 0x7fffu + ((u >> 16) & 1u)) >> 16;   // round-to-nearest-even
}
__device__ __forceinline__ unsigned int pack2bf(float lo, float hi) {
    return f2bf_rne(lo) | (f2bf_rne(hi) << 16);
}

// ---------------------------------------------------------------------------
// Fused prep + transpose (identical to R5 — no atomics, no queues).
// ---------------------------------------------------------------------------
__global__ __launch_bounds__(256) void prep_transpose_kernel(
    const float* __restrict__ lw, const int* __restrict__ rows,
    const int* __restrict__ cols, const float* __restrict__ ll,
    uint2* __restrict__ cw, int* __restrict__ rs,
    unsigned int* __restrict__ cet32) {
    int bid = blockIdx.x;
    int t = threadIdx.x;
    if (bid < PREP_BLOCKS) {
        int e = bid * 256 + t;
        if (e < NSE_) {
            cw[e] = make_uint2((unsigned)cols[e],
                               __float_as_uint(__expf(lw[e])));
            if (e == 0) { rs[0] = 0; rs[NN] = NSE_; }
            else if (rows[e] != rows[e - 1]) rs[rows[e]] = e;
        } else if (e < NSE_ + 64) {
            cw[e] = make_uint2(0u, 0u);         // col=0 (safe), w=0
        }
        return;
    }
    bid -= PREP_BLOCKS;
    int g = bid & 7;
    int ct = bid >> 3;
    int c0 = ct * 64, b0 = g * GB;
    __shared__ unsigned int tile_u[16][68];     // [batch_pair][c_local]
    {
        int c4 = t & 15, bp = t >> 4;
        const float4 fa = *reinterpret_cast<const float4*>(
            ll + (size_t)(b0 + 2 * bp + 0) * CC + c0 + 4 * c4);
        const float4 fb = *reinterpret_cast<const float4*>(
            ll + (size_t)(b0 + 2 * bp + 1) * CC + c0 + 4 * c4);
        uint4 u;
        u.x = pack2bf(__expf(fa.x), __expf(fb.x));
        u.y = pack2bf(__expf(fa.y), __expf(fb.y));
        u.z = pack2bf(__expf(fa.z), __expf(fb.z));
        u.w = pack2bf(__expf(fa.w), __expf(fb.w));
        *reinterpret_cast<uint4*>(&tile_u[bp][4 * c4]) = u;
    }
    __syncthreads();
    {
        int c = t >> 2, q = t & 3;
        uint4 o;
        o.x = tile_u[4 * q + 0][c];
        o.y = tile_u[4 * q + 1][c];
        o.z = tile_u[4 * q + 2][c];
        o.w = tile_u[4 * q + 3][c];
        size_t base_u = ((size_t)g * CC + c0) * 16;
        *reinterpret_cast<uint4*>(cet32 + base_u + c * 16 + 4 * q) = o;
    }
}

// ---------------------------------------------------------------------------
// Main gather-accumulate. R5 skeleton (static blockIdx&7 -> g, 16-row tile,
// 4 waves) + dual-row streams: each wave runs rows (nA, nA+1) concurrently
// as independent gather streams -> 8 uint4 gathers in flight per j-loop
// (2x MLP vs R5). Tail edges masked w=0 at stage time; stale-stream gathers
// re-read a valid col (harmless, w=0).
// ---------------------------------------------------------------------------
__global__ __launch_bounds__(256) void sum_rows_kernel(
    const uint2* __restrict__ cw, const int* __restrict__ rs,
    const uint4* __restrict__ cet, float* __restrict__ out) {
    __shared__ uint2 stage[4][2][64];
    __shared__ float lds_out[32][17];
    int g = blockIdx.x & 7;             // -> XCD round-robin
    int ntile = blockIdx.x >> 3;
    int n0 = ntile * 16;
    int wv = threadIdx.x >> 6;
    int lane = threadIdx.x & 63;
    int grp = lane >> 2;                // 0..15 edge slot
    int bq = lane & 3;                  // 0..3 batch octet
    const uint4* slice = cet + (size_t)g * CC * 4;   // 4 uint4 per col
    uint2* stA = stage[wv][0];
    uint2* stB = stage[wv][1];

    for (int rp = 0; rp < 2; ++rp) {
        int nA = n0 + wv * 4 + rp * 2;              // rows nA, nA+1
        int sA = __builtin_amdgcn_readfirstlane(rs[nA]);
        int tA = __builtin_amdgcn_readfirstlane(rs[nA + 1]);
        int sB = tA;
        int tB = __builtin_amdgcn_readfirstlane(rs[nA + 2]);
        v2f aA[4], aB[4];
        aA[0] = 0.f; aA[1] = 0.f; aA[2] = 0.f; aA[3] = 0.f;
        aB[0] = 0.f; aB[1] = 0.f; aB[2] = 0.f; aB[3] = 0.f;
        float zA = 0.f, zB = 0.f;
        uint2 vA = cw[sA + lane];                   // pad-safe (64 zero pads)
        uint2 vB = cw[sB + lane];
        int ebA = sA, ebB = sB;
        while (ebA < tA || ebB < tB) {
            uint2 wA = vA, wB = vB;
            if (ebA + lane >= tA) wA.y = 0u;        // mask foreign/pad edges
            if (ebB + lane >= tB) wB.y = 0u;
            stA[lane] = wA;
            stB[lane] = wB;
            if (ebA + 64 < tA) vA = cw[ebA + 64 + lane];
            if (ebB + 64 < tB) vB = cw[ebB + 64 + lane];
            #pragma unroll
            for (int j = 0; j < 4; ++j) {
                uint2 pA = stA[j * 16 + grp];       // LDS broadcast
                uint2 pB = stB[j * 16 + grp];
                uint4 uA = slice[(pA.x << 2) | bq]; // one 64B line / 4 lanes
                uint4 uB = slice[(pB.x << 2) | bq];
                float wa = __uint_as_float(pA.y);
                float wb = __uint_as_float(pB.y);
                v2f w2a; w2a.x = wa; w2a.y = wa;
                v2f w2b; w2b.x = wb; w2b.y = wb;
                v2f q0, q1, q2, q3;
                q0.x = __uint_as_float(uA.x << 16);
                q0.y = __uint_as_float(uA.x & 0xffff0000u);
                q1.x = __uint_as_float(uA.y << 16);
                q1.y = __uint_as_float(uA.y & 0xffff0000u);
                q2.x = __uint_as_float(uA.z << 16);
                q2.y = __uint_as_float(uA.z & 0xffff0000u);
                q3.x = __uint_as_float(uA.w << 16);
                q3.y = __uint_as_float(uA.w & 0xffff0000u);
                aA[0] += w2a * q0;
                aA[1] += w2a * q1;
                aA[2] += w2a * q2;
                aA[3] += w2a * q3;
                q0.x = __uint_as_float(uB.x << 16);
                q0.y = __uint_as_float(uB.x & 0xffff0000u);
                q1.x = __uint_as_float(uB.y << 16);
                q1.y = __uint_as_float(uB.y & 0xffff0000u);
                q2.x = __uint_as_float(uB.z << 16);
                q2.y = __uint_as_float(uB.z & 0xffff0000u);
                q3.x = __uint_as_float(uB.w << 16);
                q3.y = __uint_as_float(uB.w & 0xffff0000u);
                aB[0] += w2b * q0;
                aB[1] += w2b * q1;
                aB[2] += w2b * q2;
                aB[3] += w2b * q3;
                zA += wa;
                zB += wb;
            }
            ebA += 64;
            ebB += 64;
        }
        #pragma unroll
        for (int off = 4; off <= 32; off <<= 1) {   // reduce over grp bits
            #pragma unroll
            for (int q = 0; q < 4; ++q) {
                aA[q].x += __shfl_xor(aA[q].x, off);
                aA[q].y += __shfl_xor(aA[q].y, off);
                aB[q].x += __shfl_xor(aB[q].x, off);
                aB[q].y += __shfl_xor(aB[q].y, off);
            }
            zA += __shfl_xor(zA, off);
            zB += __shfl_xor(zB, off);
        }
        if (grp == 0) {
            float lzA = __logf(zA), lzB = __logf(zB);
            int col = wv * 4 + rp * 2;
            #pragma unroll
            for (int q = 0; q < 4; ++q) {
                lds_out[bq * 8 + q * 2 + 0][col]     = __logf(aA[q].x) - lzA;
                lds_out[bq * 8 + q * 2 + 1][col]     = __logf(aA[q].y) - lzA;
                lds_out[bq * 8 + q * 2 + 0][col + 1] = __logf(aB[q].x) - lzB;
                lds_out[bq * 8 + q * 2 + 1][col + 1] = __logf(aB[q].y) - lzB;
            }
        }
    }
    __syncthreads();
    if (threadIdx.x < 128) {
        int bl = threadIdx.x >> 2, ch = threadIdx.x & 3;
        float4 v = make_float4(lds_out[bl][ch * 4 + 0], lds_out[bl][ch * 4 + 1],
                               lds_out[bl][ch * 4 + 2], lds_out[bl][ch * 4 + 3]);
        *reinterpret_cast<float4*>(
            out + (size_t)(g * GB + bl) * NN + n0 + ch * 4) = v;
    }
}

// ---------------------------------------------------------------------------
extern "C" void kernel_launch(void* const* d_in, const int* in_sizes, int n_in,
                              void* d_out, int out_size, void* d_ws, size_t ws_size,
                              hipStream_t stream) {
    const float* child_ll = (const float*)d_in[0];   // [B, C]
    const float* log_w    = (const float*)d_in[1];   // [NSE]
    const int*   rows     = (const int*)  d_in[2];   // [NSE] sorted
    const int*   cols     = (const int*)  d_in[3];   // [NSE]
    float* out = (float*)d_out;                      // [B, N]

    // ws: [0,6MiB) cw uint2[NSE+64] | [6MiB,+33KB) rs | [8MiB,24MiB) cet bf16
    char* ws = (char*)d_ws;
    uint2*        cwp = (uint2*)ws;
    int*          rs  = (int*)(ws + (size_t)6 * 1024 * 1024);
    unsigned int* cet = (unsigned int*)(ws + (size_t)8 * 1024 * 1024);

    prep_transpose_kernel<<<PREP_BLOCKS + TP_BLOCKS, 256, 0, stream>>>(
        log_w, rows, cols, child_ll, cwp, rs, cet);
    sum_rows_kernel<<<(NN / 16) * 8, 256, 0, stream>>>(
        cwp, rs, (const uint4*)cet, out);
}

// Round 8
// 125.304 us; speedup vs baseline: 2.6921x; 1.0562x over previous
//
#include <hip/hip_runtime.h>
#include <hip/hip_bf16.h>

// B=256 batch, N=8192 rows, C=32768 cols, NSE=524288 edges (rows sorted,
// every row present at least once).
#define BB   256
#define NN   8192
#define CC   32768
#define NSE_ 524288
#define GB   64                                 // batches per group (4 groups)
#define PREP_BLOCKS ((NSE_ + 64 + 255) / 256)   // 2049
#define TP_BLOCKS   ((CC / 64) * 4)             // 2048

typedef float v2f __attribute__((ext_vector_type(2)));

#define FP8_SCALE  8.0f
#define LOG_SCALE  2.0794415416798357f          // ln(8)

__device__ __forceinline__ unsigned int pack4_fp8(float a, float b, float c,
                                                  float d) {
    int v = __builtin_amdgcn_cvt_pk_fp8_f32(a, b, 0, false);
    v = __builtin_amdgcn_cvt_pk_fp8_f32(c, d, v, true);
    return (unsigned)v;
}

// ---------------------------------------------------------------------------
// Fused prep + transpose.
//  [0, PREP_BLOCKS): cw[e]=(col, exp(log_w)) uint2 (+64 zero pads), CSR
//                    row_start from sorted rows.
//  [PREP_BLOCKS, +TP_BLOCKS): cet[g][c][b] = e4m3(8*exp(ll[g*64+b][c])),
//    layout [4][CC][64] bytes (one 64B line per (g, col)).
// ---------------------------------------------------------------------------
__global__ __launch_bounds__(256) void prep_transpose_kernel(
    const float* __restrict__ lw, const int* __restrict__ rows,
    const int* __restrict__ cols, const float* __restrict__ ll,
    uint2* __restrict__ cw, int* __restrict__ rs,
    unsigned char* __restrict__ cet) {
    int bid = blockIdx.x;
    int t = threadIdx.x;
    if (bid < PREP_BLOCKS) {
        int e = bid * 256 + t;
        if (e < NSE_) {
            cw[e] = make_uint2((unsigned)cols[e],
                               __float_as_uint(__expf(lw[e])));
            if (e == 0) { rs[0] = 0; rs[NN] = NSE_; }
            else if (rows[e] != rows[e - 1]) rs[rows[e]] = e;
        } else if (e < NSE_ + 64) {
            cw[e] = make_uint2(0u, 0u);         // col=0 (safe), w=0
        }
        return;
    }
    bid -= PREP_BLOCKS;
    int g = bid & 3;
    int ct = bid >> 2;
    int c0 = ct * 64, b0 = g * GB;
    __shared__ float tile[64][65];              // [c_local][b_local]
    #pragma unroll
    for (int k = 0; k < 4; ++k) {
        int row = (t >> 4) + 16 * k;            // 0..63 batch row
        int c4 = t & 15;                        // float4 slot along C
        const float4 v = *reinterpret_cast<const float4*>(
            ll + (size_t)(b0 + row) * CC + c0 + 4 * c4);
        tile[c4 * 4 + 0][row] = v.x;
        tile[c4 * 4 + 1][row] = v.y;
        tile[c4 * 4 + 2][row] = v.z;
        tile[c4 * 4 + 3][row] = v.w;
    }
    __syncthreads();
    {
        int cl = t >> 2, q = t & 3;             // col local, 16-batch quarter
        unsigned int o[4];
        #pragma unroll
        for (int i = 0; i < 4; ++i) {
            int b = q * 16 + i * 4;
            o[i] = pack4_fp8(__expf(tile[cl][b + 0]) * FP8_SCALE,
                             __expf(tile[cl][b + 1]) * FP8_SCALE,
                             __expf(tile[cl][b + 2]) * FP8_SCALE,
                             __expf(tile[cl][b + 3]) * FP8_SCALE);
        }
        uint4 u4 = make_uint4(o[0], o[1], o[2], o[3]);
        *reinterpret_cast<uint4*>(
            cet + ((size_t)g * CC + c0 + cl) * GB + q * 16) = u4;
    }
}

// ---------------------------------------------------------------------------
// Main gather-accumulate. Block = (16-row tile, g), g in 0..3 (blockIdx&3:
// each XCD statically serves one g; slice = CC*64B = 2 MiB, L2-resident).
// 4 waves x 4 rows. Lane = (grp = lane>>2 edge slot 0..15, bq = lane&3).
// Per 64-edge chunk: one coalesced cw load staged in wave-private LDS,
// 4 uint4 gathers (16 edges x one 64B fp8 line / 4 lanes); each lane
// decodes 16 fp8 batches via HW v_cvt_pk_f32_fp8 + v_pk_fma_f32.
// Tail edges masked w=0 at stage time (cw zero-padded).
// ---------------------------------------------------------------------------
__global__ __launch_bounds__(256) void sum_rows_kernel(
    const uint2* __restrict__ cw, const int* __restrict__ rs,
    const uint4* __restrict__ cet, float* __restrict__ out) {
    __shared__ uint2 stage[4][64];
    __shared__ float lds_out[64][17];
    int g = blockIdx.x & 3;             // one g per XCD (b&7 -> XCD, b&3 = g)
    int ntile = blockIdx.x >> 2;
    int n0 = ntile * 16;
    int wv = threadIdx.x >> 6;
    int lane = threadIdx.x & 63;
    int grp = lane >> 2;                // 0..15 edge slot
    int bq = lane & 3;                  // 0..3 sixteen-batch quarter
    const uint4* slice = cet + (size_t)g * CC * 4;   // 4 uint4 per col
    uint2* st = stage[wv];

    for (int r = 0; r < 4; ++r) {
        int n = n0 + wv * 4 + r;
        int s = __builtin_amdgcn_readfirstlane(rs[n]);
        int t = __builtin_amdgcn_readfirstlane(rs[n + 1]);
        v2f acc[8];
        #pragma unroll
        for (int k = 0; k < 8; ++k) acc[k] = 0.f;
        float zs = 0.f;
        uint2 v = cw[s + lane];                     // pad-safe (64 zero pads)
        for (int eb = s; eb < t; eb += 64) {
            if (eb + lane >= t) v.y = 0u;           // mask foreign/pad edges
            st[lane] = v;                           // wave-private
            if (eb + 64 < t) v = cw[eb + 64 + lane];   // prefetch next chunk
            #pragma unroll
            for (int j = 0; j < 4; ++j) {
                uint2 p = st[j * 16 + grp];         // LDS broadcast
                float w = __uint_as_float(p.y);
                uint4 u = slice[(p.x << 2) | bq];   // 64B fp8 line / 4 lanes
                v2f w2; w2.x = w; w2.y = w;
                acc[0] += w2 * __builtin_amdgcn_cvt_pk_f32_fp8(u.x, false);
                acc[1] += w2 * __builtin_amdgcn_cvt_pk_f32_fp8(u.x, true);
                acc[2] += w2 * __builtin_amdgcn_cvt_pk_f32_fp8(u.y, false);
                acc[3] += w2 * __builtin_amdgcn_cvt_pk_f32_fp8(u.y, true);
                acc[4] += w2 * __builtin_amdgcn_cvt_pk_f32_fp8(u.z, false);
                acc[5] += w2 * __builtin_amdgcn_cvt_pk_f32_fp8(u.z, true);
                acc[6] += w2 * __builtin_amdgcn_cvt_pk_f32_fp8(u.w, false);
                acc[7] += w2 * __builtin_amdgcn_cvt_pk_f32_fp8(u.w, true);
                zs += w;
            }
        }
        #pragma unroll
        for (int off = 4; off <= 32; off <<= 1) {   // reduce over grp bits
            #pragma unroll
            for (int k = 0; k < 8; ++k) {
                acc[k].x += __shfl_xor(acc[k].x, off);
                acc[k].y += __shfl_xor(acc[k].y, off);
            }
            zs += __shfl_xor(zs, off);
        }
        if (grp == 0) {
            float lz = __logf(zs) + LOG_SCALE;      // acc holds 8x the sum
            int col = wv * 4 + r;
            #pragma unroll
            for (int k = 0; k < 8; ++k) {
                lds_out[bq * 16 + 2 * k + 0][col] = __logf(acc[k].x) - lz;
                lds_out[bq * 16 + 2 * k + 1][col] = __logf(acc[k].y) - lz;
            }
        }
    }
    __syncthreads();
    {
        int bl = threadIdx.x >> 2, ch = threadIdx.x & 3;   // 64 batches x 4
        float4 o = make_float4(lds_out[bl][ch * 4 + 0], lds_out[bl][ch * 4 + 1],
                               lds_out[bl][ch * 4 + 2], lds_out[bl][ch * 4 + 3]);
        *reinterpret_cast<float4*>(
            out + (size_t)(g * GB + bl) * NN + n0 + ch * 4) = o;
    }
}

// ---------------------------------------------------------------------------
extern "C" void kernel_launch(void* const* d_in, const int* in_sizes, int n_in,
                              void* d_out, int out_size, void* d_ws, size_t ws_size,
                              hipStream_t stream) {
    const float* child_ll = (const float*)d_in[0];   // [B, C]
    const float* log_w    = (const float*)d_in[1];   // [NSE]
    const int*   rows     = (const int*)  d_in[2];   // [NSE] sorted
    const int*   cols     = (const int*)  d_in[3];   // [NSE]
    float* out = (float*)d_out;                      // [B, N]

    // ws: [0,4.5MiB) cw uint2[NSE+64] | [5MiB,+33KB) rs | [6MiB,14MiB) cet fp8
    char* ws = (char*)d_ws;
    uint2*         cwp = (uint2*)ws;
    int*           rs  = (int*)(ws + (size_t)5 * 1024 * 1024);
    unsigned char* cet = (unsigned char*)(ws + (size_t)6 * 1024 * 1024);

    prep_transpose_kernel<<<PREP_BLOCKS + TP_BLOCKS, 256, 0, stream>>>(
        log_w, rows, cols, child_ll, cwp, rs, cet);
    sum_rows_kernel<<<(NN / 16) * 4, 256, 0, stream>>>(
        cwp, rs, (const uint4*)cet, out);
}

// Round 9
// 121.699 us; speedup vs baseline: 2.7719x; 1.0296x over previous
//
#include <hip/hip_runtime.h>
#include <hip/hip_bf16.h>

// B=256 batch, N=8192 rows, C=32768 cols, NSE=524288 edges (rows sorted,
// every row present at least once).
#define BB   256
#define NN   8192
#define CC   32768
#define NSE_ 524288
#define GB   64                                 // batches per group (4 groups)
#define PREP_BLOCKS ((NSE_ + 64 + 255) / 256)   // 2049
#define TP_BLOCKS   ((CC / 64) * 4)             // 2048

typedef float v2f __attribute__((ext_vector_type(2)));

#define FP8_SCALE  8.0f
#define LOG_SCALE  2.0794415416798357f          // ln(8)

__device__ __forceinline__ unsigned int pack4_fp8(float a, float b, float c,
                                                  float d) {
    int v = __builtin_amdgcn_cvt_pk_fp8_f32(a, b, 0, false);
    v = __builtin_amdgcn_cvt_pk_fp8_f32(c, d, v, true);
    return (unsigned)v;
}

// ---------------------------------------------------------------------------
// Fused prep + transpose (numerically identical to R8).
//  [0, PREP_BLOCKS): cw[e]=(col, exp(log_w)) uint2 (+64 zero pads), CSR
//                    row_start from sorted rows.
//  [PREP_BLOCKS, +TP_BLOCKS): cet[g][c][b] = e4m3(8*exp(ll[g*64+b][c])),
//    layout [4][CC][64] bytes (one 64B line per (g, col)).
// ---------------------------------------------------------------------------
__global__ __launch_bounds__(256) void prep_transpose_kernel(
    const float* __restrict__ lw, const int* __restrict__ rows,
    const int* __restrict__ cols, const float* __restrict__ ll,
    uint2* __restrict__ cw, int* __restrict__ rs,
    unsigned char* __restrict__ cet) {
    int bid = blockIdx.x;
    int t = threadIdx.x;
    if (bid < PREP_BLOCKS) {
        int e = bid * 256 + t;
        if (e < NSE_) {
            cw[e] = make_uint2((unsigned)cols[e],
                               __float_as_uint(__expf(lw[e])));
            if (e == 0) { rs[0] = 0; rs[NN] = NSE_; }
            else if (rows[e] != rows[e - 1]) rs[rows[e]] = e;
        } else if (e < NSE_ + 64) {
            cw[e] = make_uint2(0u, 0u);         // col=0 (safe), w=0
        }
        return;
    }
    bid -= PREP_BLOCKS;
    int g = bid & 3;
    int ct = bid >> 2;
    int c0 = ct * 64, b0 = g * GB;
    __shared__ float tile[64][65];              // [c_local][b_local]
    #pragma unroll
    for (int k = 0; k < 4; ++k) {
        int row = (t >> 4) + 16 * k;            // 0..63 batch row
        int c4 = t & 15;                        // float4 slot along C
        const float4 v = *reinterpret_cast<const float4*>(
            ll + (size_t)(b0 + row) * CC + c0 + 4 * c4);
        tile[c4 * 4 + 0][row] = v.x;
        tile[c4 * 4 + 1][row] = v.y;
        tile[c4 * 4 + 2][row] = v.z;
        tile[c4 * 4 + 3][row] = v.w;
    }
    __syncthreads();
    {
        int cl = t >> 2, q = t & 3;             // col local, 16-batch quarter
        unsigned int o[4];
        #pragma unroll
        for (int i = 0; i < 4; ++i) {
            int b = q * 16 + i * 4;
            o[i] = pack4_fp8(__expf(tile[cl][b + 0]) * FP8_SCALE,
                             __expf(tile[cl][b + 1]) * FP8_SCALE,
                             __expf(tile[cl][b + 2]) * FP8_SCALE,
                             __expf(tile[cl][b + 3]) * FP8_SCALE);
        }
        uint4 u4 = make_uint4(o[0], o[1], o[2], o[3]);
        *reinterpret_cast<uint4*>(
            cet + ((size_t)g * CC + c0 + cl) * GB + q * 16) = u4;
    }
}

// ---------------------------------------------------------------------------
// Main gather-accumulate. Block = (16-row tile, g), g in 0..3; each XCD's
// gathers stay in one 2 MiB L2-resident fp8 slice. 4 waves x 4 rows.
// Lane = (grp = lane>>2 edge slot 0..15, bq = lane&3 sixteen-batch quarter).
// R9: full 64-edge chunks run UNPREDICATED (no mask VALU); the tail runs
// only ceil(rem/16) 16-edge steps instead of always 4 — cuts the ~1.5x
// ceil-to-64 step inflation to ~1.125x with bit-identical results
// (skipped steps only ever contributed exact +0.0).
// ---------------------------------------------------------------------------
__global__ __launch_bounds__(256) void sum_rows_kernel(
    const uint2* __restrict__ cw, const int* __restrict__ rs,
    const uint4* __restrict__ cet, float* __restrict__ out) {
    __shared__ uint2 stage[4][64];
    __shared__ float lds_out[64][17];
    int g = blockIdx.x & 3;
    int ntile = blockIdx.x >> 2;
    int n0 = ntile * 16;
    int wv = threadIdx.x >> 6;
    int lane = threadIdx.x & 63;
    int grp = lane >> 2;                // 0..15 edge slot
    int bq = lane & 3;                  // 0..3 sixteen-batch quarter
    const uint4* slice = cet + (size_t)g * CC * 4;   // 4 uint4 per col
    uint2* st = stage[wv];

    for (int r = 0; r < 4; ++r) {
        int n = n0 + wv * 4 + r;
        int s = __builtin_amdgcn_readfirstlane(rs[n]);
        int t = __builtin_amdgcn_readfirstlane(rs[n + 1]);
        v2f acc[8];
        #pragma unroll
        for (int k = 0; k < 8; ++k) acc[k] = 0.f;
        float zs = 0.f;
        uint2 v = cw[s + lane];                 // pad-safe (64 zero pads)
        int eb = s;
        // ---- full 64-edge chunks: unpredicated ----
        for (; eb + 64 <= t; eb += 64) {
            st[lane] = v;                       // wave-private stage
            v = cw[eb + 64 + lane];             // prefetch (pad-safe)
            #pragma unroll
            for (int j = 0; j < 4; ++j) {
                uint2 p = st[j * 16 + grp];     // LDS broadcast
                float w = __uint_as_float(p.y);
                uint4 u = slice[(p.x << 2) | bq];   // 64B fp8 line / 4 lanes
                v2f w2; w2.x = w; w2.y = w;
                acc[0] += w2 * __builtin_amdgcn_cvt_pk_f32_fp8(u.x, false);
                acc[1] += w2 * __builtin_amdgcn_cvt_pk_f32_fp8(u.x, true);
                acc[2] += w2 * __builtin_amdgcn_cvt_pk_f32_fp8(u.y, false);
                acc[3] += w2 * __builtin_amdgcn_cvt_pk_f32_fp8(u.y, true);
                acc[4] += w2 * __builtin_amdgcn_cvt_pk_f32_fp8(u.z, false);
                acc[5] += w2 * __builtin_amdgcn_cvt_pk_f32_fp8(u.z, true);
                acc[6] += w2 * __builtin_amdgcn_cvt_pk_f32_fp8(u.w, false);
                acc[7] += w2 * __builtin_amdgcn_cvt_pk_f32_fp8(u.w, true);
                zs += w;
            }
        }
        // ---- tail: rem in (0,64); only ceil(rem/16) steps ----
        int rem = t - eb;
        if (rem > 0) {
            if (eb + lane >= t) v.y = 0u;       // mask foreign/pad edges
            st[lane] = v;
            int msteps = (rem + 15) >> 4;       // 1..4
            for (int j = 0; j < msteps; ++j) {
                uint2 p = st[j * 16 + grp];
                float w = __uint_as_float(p.y);
                uint4 u = slice[(p.x << 2) | bq];
                v2f w2; w2.x = w; w2.y = w;
                acc[0] += w2 * __builtin_amdgcn_cvt_pk_f32_fp8(u.x, false);
                acc[1] += w2 * __builtin_amdgcn_cvt_pk_f32_fp8(u.x, true);
                acc[2] += w2 * __builtin_amdgcn_cvt_pk_f32_fp8(u.y, false);
                acc[3] += w2 * __builtin_amdgcn_cvt_pk_f32_fp8(u.y, true);
                acc[4] += w2 * __builtin_amdgcn_cvt_pk_f32_fp8(u.z, false);
                acc[5] += w2 * __builtin_amdgcn_cvt_pk_f32_fp8(u.z, true);
                acc[6] += w2 * __builtin_amdgcn_cvt_pk_f32_fp8(u.w, false);
                acc[7] += w2 * __builtin_amdgcn_cvt_pk_f32_fp8(u.w, true);
                zs += w;
            }
        }
        #pragma unroll
        for (int off = 4; off <= 32; off <<= 1) {   // reduce over grp bits
            #pragma unroll
            for (int k = 0; k < 8; ++k) {
                acc[k].x += __shfl_xor(acc[k].x, off);
                acc[k].y += __shfl_xor(acc[k].y, off);
            }
            zs += __shfl_xor(zs, off);
        }
        if (grp == 0) {
            float lz = __logf(zs) + LOG_SCALE;      // acc holds 8x the sum
            int col = wv * 4 + r;
            #pragma unroll
            for (int k = 0; k < 8; ++k) {
                lds_out[bq * 16 + 2 * k + 0][col] = __logf(acc[k].x) - lz;
                lds_out[bq * 16 + 2 * k + 1][col] = __logf(acc[k].y) - lz;
            }
        }
    }
    __syncthreads();
    {
        int bl = threadIdx.x >> 2, ch = threadIdx.x & 3;   // 64 batches x 4
        float4 o = make_float4(lds_out[bl][ch * 4 + 0], lds_out[bl][ch * 4 + 1],
                               lds_out[bl][ch * 4 + 2], lds_out[bl][ch * 4 + 3]);
        *reinterpret_cast<float4*>(
            out + (size_t)(g * GB + bl) * NN + n0 + ch * 4) = o;
    }
}

// ---------------------------------------------------------------------------
extern "C" void kernel_launch(void* const* d_in, const int* in_sizes, int n_in,
                              void* d_out, int out_size, void* d_ws, size_t ws_size,
                              hipStream_t stream) {
    const float* child_ll = (const float*)d_in[0];   // [B, C]
    const float* log_w    = (const float*)d_in[1];   // [NSE]
    const int*   rows     = (const int*)  d_in[2];   // [NSE] sorted
    const int*   cols     = (const int*)  d_in[3];   // [NSE]
    float* out = (float*)d_out;                      // [B, N]

    // ws: [0,4.5MiB) cw uint2[NSE+64] | [5MiB,+33KB) rs | [6MiB,14MiB) cet fp8
    char* ws = (char*)d_ws;
    uint2*         cwp = (uint2*)ws;
    int*           rs  = (int*)(ws + (size_t)5 * 1024 * 1024);
    unsigned char* cet = (unsigned char*)(ws + (size_t)6 * 1024 * 1024);

    prep_transpose_kernel<<<PREP_BLOCKS + TP_BLOCKS, 256, 0, stream>>>(
        log_w, rows, cols, child_ll, cwp, rs, cet);
    sum_rows_kernel<<<(NN / 16) * 4, 256, 0, stream>>>(
        cwp, rs, (const uint4*)cet, out);
}